// Round 8
// baseline (1337.082 us; speedup 1.0000x reference)
//
#include <hip/hip_runtime.h>
#include <hip/hip_cooperative_groups.h>
#include <math.h>

namespace cg = cooperative_groups;

#define N_NODES  30000
#define N_EDGES  240000
#define E_TOT    270000   // N_EDGES + N_NODES self loops
#define N_GRAPHS 300
#define N_PHASES 13

typedef _Float16 half8 __attribute__((ext_vector_type(8)));
typedef _Float16 half4 __attribute__((ext_vector_type(4)));
typedef _Float16 half2v __attribute__((ext_vector_type(2)));
typedef float float4v __attribute__((ext_vector_type(4)));

struct Params {
    const float* x; const int* ei; const int* batch;
    const float *w_in, *b_in, *bn_in;
    const float *g1_wl, *g1_bl, *g1_wr, *g1_br, *g1_att, *g1_bias, *bn1;
    const float *g2_wl, *g2_bl, *g2_wr, *g2_br, *g2_att, *g2_bias, *bn2;
    const float *g3_wl, *g3_bl, *g3_wr, *g3_br, *g3_att, *g3_bias, *bn3;
    const float *c_w1, *c_b1, *c_bn, *c_w2, *c_b2, *c_w3, *c_b3;
    float* out;
    _Float16 *a16, *xl16, *xr16;
    _Float16 *wt1l, *wt1r, *wt2l, *wt2r, *wt3l, *wt3r;
    float* bufD;
    int *deg, *cnt, *slocal, *bsums, *row_start, *esrc, *gdeg, *gstart;
};

// LDS budget: GEMM As[128][72] f16 (18432 B) + Bs[64][72] f16 (9216 B) = 27648 B
#define SMEM_BYTES 27648

// ---------------------------------------------------------------------------
// weight transpose helper (grid-stride elementwise)
// ---------------------------------------------------------------------------
__device__ inline void wp_dev(const float* __restrict__ W, _Float16* __restrict__ Wt,
                              int K, int CO, int gtid, int T) {
    int tot = K * CO;
    for (int i = gtid; i < tot; i += T) {
        int k = i / CO, c = i - k * CO;
        Wt[(size_t)c * K + k] = (_Float16)W[i];
    }
}

// ---------------------------------------------------------------------------
// MFMA f16 GEMM phase: grid-stride over (m-tile, matrix, col-slice) tiles.
// BM=128 x BN=64, BK=64, 4 waves: wave w owns rows [32w,32w+32) as
// 2 m-frags x 4 n-frags of mfma_f32_16x16x32_f16 (fp32 accumulate).
// ---------------------------------------------------------------------------
template<int K, int COUT>
__device__ void gemm_phase(const _Float16* __restrict__ A,
                           const _Float16* __restrict__ Wtl, const float* __restrict__ bl,
                           const _Float16* __restrict__ Wtr, const float* __restrict__ br,
                           _Float16* __restrict__ outl, _Float16* __restrict__ outr,
                           char* smem) {
    _Float16 (*As)[72] = (_Float16(*)[72])smem;
    _Float16 (*Bs)[72] = (_Float16(*)[72])(smem + 128 * 72 * 2);
    const int tid  = threadIdx.x;
    const int wave = tid >> 6;
    const int lane = tid & 63;
    const int l15  = lane & 15;
    const int lq   = lane >> 4;
    constexpr int NSL = COUT / 64;              // col slices per matrix (4 or 2)
    const int NTM = (N_NODES + 127) >> 7;       // 235
    const int TOT = NTM * NSL * 2;
    for (int t = blockIdx.x; t < TOT; t += gridDim.x) {
        int mt  = t / (NSL * 2);
        int rem = t - mt * (NSL * 2);
        int sel = rem / NSL;
        int col0 = (rem - sel * NSL) * 64;
        const _Float16* Wt = sel ? Wtr : Wtl;
        const float* bias  = sel ? br : bl;
        _Float16* out      = sel ? outr : outl;
        int n0 = mt * 128;
        float4v acc[2][4] = {};
        for (int kt = 0; kt < K; kt += 64) {
            // stage A: 128 rows x 64 f16 in 4 passes of 256 thr x 8 f16
#pragma unroll
            for (int pp = 0; pp < 4; ++pp) {
                int idx = pp * 256 + tid;
                int row = idx >> 3, ch = (idx & 7) * 8;
                int gn = n0 + row;
                half8 v = {};
                if (gn < N_NODES) v = *(const half8*)(A + (size_t)gn * K + kt + ch);
                *(half8*)(&As[row][ch]) = v;
            }
            // stage B: 64 rows x 64 f16 in 2 passes
#pragma unroll
            for (int pp = 0; pp < 2; ++pp) {
                int idx = pp * 256 + tid;
                int row = idx >> 3, ch = (idx & 7) * 8;
                half8 v = *(const half8*)(Wt + (size_t)(col0 + row) * K + kt + ch);
                *(half8*)(&Bs[row][ch]) = v;
            }
            __syncthreads();
#pragma unroll
            for (int kk = 0; kk < 64; kk += 32) {
                half8 af0 = *(const half8*)(&As[wave * 32 + l15][kk + lq * 8]);
                half8 af1 = *(const half8*)(&As[wave * 32 + 16 + l15][kk + lq * 8]);
#pragma unroll
                for (int nt = 0; nt < 4; ++nt) {
                    half8 bf = *(const half8*)(&Bs[nt * 16 + l15][kk + lq * 8]);
                    acc[0][nt] = __builtin_amdgcn_mfma_f32_16x16x32_f16(af0, bf, acc[0][nt], 0, 0, 0);
                    acc[1][nt] = __builtin_amdgcn_mfma_f32_16x16x32_f16(af1, bf, acc[1][nt], 0, 0, 0);
                }
            }
            __syncthreads();
        }
#pragma unroll
        for (int mi = 0; mi < 2; ++mi)
#pragma unroll
            for (int nt = 0; nt < 4; ++nt) {
                int col = col0 + nt * 16 + l15;
                float bv = bias[col];
#pragma unroll
                for (int r = 0; r < 4; ++r) {
                    int row = n0 + wave * 32 + mi * 16 + lq * 4 + r;
                    if (row < N_NODES)
                        out[(size_t)row * COUT + col] = (_Float16)(acc[mi][nt][r] + bv);
                }
            }
    }
}

// ---------------------------------------------------------------------------
// fused GATv2 gather phase: wave per node (grid-stride), all H heads,
// 4-edge-unrolled online softmax, bias+bn+elu epilogue. No atomics.
// ---------------------------------------------------------------------------
template<int H, int C, typename TOUT>
__device__ void gather_phase(const _Float16* __restrict__ xl, const _Float16* __restrict__ xr,
                             const int* __restrict__ row_start, const int* __restrict__ esrc,
                             const float* __restrict__ att, const float* __restrict__ gbias,
                             const float* __restrict__ bnp, TOUT* __restrict__ out) {
    constexpr int HC    = H * C;
    constexpr int PER   = HC / 64;
    constexpr int GROUP = 64 / H;
    const int lane = threadIdx.x & 63;
    const int wv   = blockIdx.x * (blockDim.x >> 6) + (threadIdx.x >> 6);
    const int NW   = gridDim.x * (blockDim.x >> 6);
    const int base = lane * PER;

    float av[PER];
    if constexpr (PER == 4) *(float4*)av = *(const float4*)(att + base);
    else                    *(float2*)av = *(const float2*)(att + base);

    for (int node = wv; node < N_NODES; node += NW) {
        float rr[PER], acc[PER];
        if constexpr (PER == 4) {
            half4 rv = *(const half4*)(xr + (size_t)node * HC + base);
#pragma unroll
            for (int k = 0; k < PER; ++k) rr[k] = (float)rv[k];
        } else {
            half2v rv = *(const half2v*)(xr + (size_t)node * HC + base);
#pragma unroll
            for (int k = 0; k < PER; ++k) rr[k] = (float)rv[k];
        }
#pragma unroll
        for (int k = 0; k < PER; ++k) acc[k] = 0.f;

        float m = -INFINITY, l = 0.f;
        const int j0 = row_start[node], j1 = row_start[node + 1];
        for (int jc = j0; jc < j1; jc += 64) {
            int nedge = min(64, j1 - jc);
            int ev = (jc + lane < j1) ? esrc[jc + lane] : 0;
            int jj = 0;
            for (; jj + 4 <= nedge; jj += 4) {
                int s[4];
#pragma unroll
                for (int u = 0; u < 4; ++u) s[u] = __shfl(ev, jj + u, 64);
                float xs[4][PER];
#pragma unroll
                for (int u = 0; u < 4; ++u) {
                    if constexpr (PER == 4) {
                        half4 xv = *(const half4*)(xl + (size_t)s[u] * HC + base);
#pragma unroll
                        for (int k = 0; k < PER; ++k) xs[u][k] = (float)xv[k];
                    } else {
                        half2v xv = *(const half2v*)(xl + (size_t)s[u] * HC + base);
#pragma unroll
                        for (int k = 0; k < PER; ++k) xs[u][k] = (float)xv[k];
                    }
                }
                float pz[4];
#pragma unroll
                for (int u = 0; u < 4; ++u) {
                    float pp = 0.f;
#pragma unroll
                    for (int k = 0; k < PER; ++k) {
                        float v = xs[u][k] + rr[k];
                        v = (v > 0.f) ? v : 0.2f * v;
                        pp = fmaf(v, av[k], pp);
                    }
                    pz[u] = pp;
                }
#pragma unroll
                for (int off = GROUP / 2; off; off >>= 1) {
#pragma unroll
                    for (int u = 0; u < 4; ++u) pz[u] += __shfl_xor(pz[u], off, 64);
                }
                float mx = fmaxf(fmaxf(pz[0], pz[1]), fmaxf(pz[2], pz[3]));
                float mn = fmaxf(m, mx);
                float scale = __expf(m - mn);
                float w[4];
#pragma unroll
                for (int u = 0; u < 4; ++u) w[u] = __expf(pz[u] - mn);
                l = fmaf(l, scale, (w[0] + w[1]) + (w[2] + w[3]));
#pragma unroll
                for (int k = 0; k < PER; ++k) {
                    float tt = fmaf(w[0], xs[0][k],
                               fmaf(w[1], xs[1][k],
                               fmaf(w[2], xs[2][k], w[3] * xs[3][k])));
                    acc[k] = fmaf(acc[k], scale, tt);
                }
                m = mn;
            }
            for (; jj < nedge; ++jj) {
                int s = __shfl(ev, jj, 64);
                float xls[PER];
                if constexpr (PER == 4) {
                    half4 xv = *(const half4*)(xl + (size_t)s * HC + base);
#pragma unroll
                    for (int k = 0; k < PER; ++k) xls[k] = (float)xv[k];
                } else {
                    half2v xv = *(const half2v*)(xl + (size_t)s * HC + base);
#pragma unroll
                    for (int k = 0; k < PER; ++k) xls[k] = (float)xv[k];
                }
                float pp = 0.f;
#pragma unroll
                for (int k = 0; k < PER; ++k) {
                    float v = xls[k] + rr[k];
                    v = (v > 0.f) ? v : 0.2f * v;
                    pp = fmaf(v, av[k], pp);
                }
#pragma unroll
                for (int off = GROUP / 2; off; off >>= 1) pp += __shfl_xor(pp, off, 64);
                float mn    = fmaxf(m, pp);
                float scale = __expf(m - mn);
                float w     = __expf(pp - mn);
                l = fmaf(l, scale, w);
#pragma unroll
                for (int k = 0; k < PER; ++k) acc[k] = fmaf(acc[k], scale, w * xls[k]);
                m = mn;
            }
        }
        float inv = 1.f / (l + 1e-16f);
        float o[PER];
#pragma unroll
        for (int k = 0; k < PER; ++k) {
            float v = fmaf(acc[k], inv, gbias[base + k]);
            float g  = bnp[base + k], be = bnp[HC + base + k];
            float mm = bnp[2 * HC + base + k], va = bnp[3 * HC + base + k];
            v = g * (v - mm) * rsqrtf(va + 1e-5f) + be;
            o[k] = (v > 0.f) ? v : (__expf(v) - 1.f);
        }
        if constexpr (sizeof(TOUT) == 2) {
            if constexpr (PER == 4) {
                half4 ov;
#pragma unroll
                for (int k = 0; k < PER; ++k) ov[k] = (_Float16)o[k];
                *(half4*)((_Float16*)out + (size_t)node * HC + base) = ov;
            } else {
                half2v ov;
#pragma unroll
                for (int k = 0; k < PER; ++k) ov[k] = (_Float16)o[k];
                *(half2v*)((_Float16*)out + (size_t)node * HC + base) = ov;
            }
        } else {
            if constexpr (PER == 4)
                *(float4*)((float*)out + (size_t)node * HC + base) = *(float4*)o;
            else
                *(float2*)((float*)out + (size_t)node * HC + base) = *(float2*)o;
        }
    }
}

// ---------------------------------------------------------------------------
// phase dispatcher (shared by cooperative mega-kernel and fallback launches)
// ---------------------------------------------------------------------------
__device__ void run_phase(const Params& p, int ph, char* smem) {
    const int gtid = blockIdx.x * blockDim.x + threadIdx.x;
    const int T    = gridDim.x * blockDim.x;
    const int NCH  = (N_NODES + 255) >> 8;      // 118 scan chunks

    switch (ph) {
    case 0: {   // zero counters + weight transposes
        for (int i = gtid; i < N_NODES; i += T) { p.deg[i] = 0; p.cnt[i] = 0; }
        for (int i = gtid; i < N_GRAPHS; i += T) p.gdeg[i] = 0;
        wp_dev(p.g1_wl, p.wt1l, 64, 256, gtid, T);
        wp_dev(p.g1_wr, p.wt1r, 64, 256, gtid, T);
        wp_dev(p.g2_wl, p.wt2l, 256, 256, gtid, T);
        wp_dev(p.g2_wr, p.wt2r, 256, 256, gtid, T);
        wp_dev(p.g3_wl, p.wt3l, 256, 128, gtid, T);
        wp_dev(p.g3_wr, p.wt3r, 256, 128, gtid, T);
    } break;
    case 1: {   // degree/graph histograms + input-layer GEMM (K=5)
        for (int e = gtid; e < E_TOT; e += T) {
            int d = (e < N_EDGES) ? p.ei[N_EDGES + e] : e - N_EDGES;
            atomicAdd(&p.deg[d], 1);
        }
        for (int i = gtid; i < N_NODES; i += T) atomicAdd(&p.gdeg[p.batch[i]], 1);
        int lane = threadIdx.x & 63;
        int wv = blockIdx.x * (blockDim.x >> 6) + (threadIdx.x >> 6);
        int NW = gridDim.x * (blockDim.x >> 6);
        for (int n = wv; n < N_NODES; n += NW) {
            float xv = (lane < 5) ? p.x[n * 5 + lane] : 0.f;
            float acc = p.b_in[lane];
#pragma unroll
            for (int ci = 0; ci < 5; ++ci)
                acc = fmaf(__shfl(xv, ci, 64), p.w_in[ci * 64 + lane], acc);
            float g = p.bn_in[lane], be = p.bn_in[64 + lane];
            float m = p.bn_in[128 + lane], va = p.bn_in[192 + lane];
            acc = g * (acc - m) * rsqrtf(va + 1e-5f) + be;
            p.a16[(size_t)n * 64 + lane] = (_Float16)fmaxf(acc, 0.f);
        }
    } break;
    case 2: {   // per-chunk exclusive scan of deg
        int* s = (int*)smem;
        if (blockIdx.x < NCH) {
            int t = threadIdx.x;
            int gid = blockIdx.x * 256 + t;
            int v = (gid < N_NODES) ? p.deg[gid] : 0;
            s[t] = v;
            __syncthreads();
            for (int off = 1; off < 256; off <<= 1) {
                int u = (t >= off) ? s[t - off] : 0;
                __syncthreads();
                s[t] += u;
                __syncthreads();
            }
            if (gid < N_NODES) p.slocal[gid] = s[t] - v;
            if (t == 255) p.bsums[blockIdx.x] = s[255];
        }
    } break;
    case 3: {   // block0: scan chunk sums; block1: gstart scan (pairs)
        int* s = (int*)smem;
        if (blockIdx.x == 0) {
            int t = threadIdx.x;
            int v = (t < NCH) ? p.bsums[t] : 0;
            s[t] = v;
            __syncthreads();
            for (int off = 1; off < 256; off <<= 1) {
                int u = (t >= off) ? s[t - off] : 0;
                __syncthreads();
                s[t] += u;
                __syncthreads();
            }
            if (t < NCH) p.bsums[t] = s[t] - v;
        } else if (blockIdx.x == 1) {
            int t = threadIdx.x;
            int i0 = 2 * t, i1 = 2 * t + 1;
            int a0 = (i0 < N_GRAPHS) ? p.gdeg[i0] : 0;
            int a1 = (i1 < N_GRAPHS) ? p.gdeg[i1] : 0;
            int ps = a0 + a1;
            s[t] = ps;
            __syncthreads();
            for (int off = 1; off < 256; off <<= 1) {
                int u = (t >= off) ? s[t - off] : 0;
                __syncthreads();
                s[t] += u;
                __syncthreads();
            }
            int excl = s[t] - ps;
            if (i0 < N_GRAPHS) p.gstart[i0] = excl;
            if (i1 < N_GRAPHS) p.gstart[i1] = excl + a0;
            if (t == 0) p.gstart[N_GRAPHS] = N_NODES;
        }
    } break;
    case 4: {   // assemble row_start
        for (int i = gtid; i < N_NODES; i += T)
            p.row_start[i] = p.slocal[i] + p.bsums[i >> 8];
        if (gtid == 0) p.row_start[N_NODES] = E_TOT;
    } break;
    case 5: {   // CSR scatter
        for (int e = gtid; e < E_TOT; e += T) {
            int s, d;
            if (e < N_EDGES) { s = p.ei[e]; d = p.ei[N_EDGES + e]; }
            else             { s = e - N_EDGES; d = s; }
            int slot = p.row_start[d] + atomicAdd(&p.cnt[d], 1);
            p.esrc[slot] = s;
        }
    } break;
    case 6:
        gemm_phase<64, 256>(p.a16, p.wt1l, p.g1_bl, p.wt1r, p.g1_br, p.xl16, p.xr16, smem);
        break;
    case 7:
        gather_phase<4, 64, _Float16>(p.xl16, p.xr16, p.row_start, p.esrc,
                                      p.g1_att, p.g1_bias, p.bn1, p.a16);
        break;
    case 8:
        gemm_phase<256, 256>(p.a16, p.wt2l, p.g2_bl, p.wt2r, p.g2_br, p.xl16, p.xr16, smem);
        break;
    case 9:
        gather_phase<4, 64, _Float16>(p.xl16, p.xr16, p.row_start, p.esrc,
                                      p.g2_att, p.g2_bias, p.bn2, p.a16);
        break;
    case 10:
        gemm_phase<256, 128>(p.a16, p.wt3l, p.g3_bl, p.wt3r, p.g3_br, p.xl16, p.xr16, smem);
        break;
    case 11:
        gather_phase<1, 128, float>(p.xl16, p.xr16, p.row_start, p.esrc,
                                    p.g3_att, p.g3_bias, p.bn3, p.bufD);
        break;
    case 12: {  // fused pooling + classifier, one graph per block (grid-stride)
        float* sg  = (float*)smem;          // 256
        float* sz1 = sg + 256;              // 128
        float* sz2 = sz1 + 128;             // 64
        float* sz3 = sz2 + 64;              // 2
        int t = threadIdx.x;
        for (int g = blockIdx.x; g < N_GRAPHS; g += gridDim.x) {
            int a = p.gstart[g], b = p.gstart[g + 1];
            if (t < 128) {
                float sum = 0.f, mx = -INFINITY;
                for (int i = a; i < b; ++i) {
                    float v = p.bufD[(size_t)i * 128 + t];
                    sum += v;
                    mx = fmaxf(mx, v);
                }
                sg[t]       = sum / fmaxf((float)(b - a), 1.f);
                sg[128 + t] = (b > a) ? mx : 0.f;
            }
            __syncthreads();
            if (t < 128) {
                float acc = p.c_b1[t];
                for (int i = 0; i < 256; ++i) acc += sg[i] * p.c_w1[i * 128 + t];
                float ga = p.c_bn[t], be = p.c_bn[128 + t];
                float m = p.c_bn[256 + t], va = p.c_bn[384 + t];
                acc = ga * (acc - m) * rsqrtf(va + 1e-5f) + be;
                sz1[t] = fmaxf(acc, 0.f);
            }
            __syncthreads();
            if (t < 64) {
                float a2 = p.c_b2[t];
                for (int i = 0; i < 128; ++i) a2 += sz1[i] * p.c_w2[i * 64 + t];
                sz2[t] = fmaxf(a2, 0.f);
            }
            __syncthreads();
            if (t < 2) {
                float a3 = p.c_b3[t];
                for (int i = 0; i < 64; ++i) a3 += sz2[i] * p.c_w3[i * 2 + t];
                sz3[t] = a3;
            }
            __syncthreads();
            if (t < 2) {
                float mm = fmaxf(sz3[0], sz3[1]);
                float lse = mm + logf(expf(sz3[0] - mm) + expf(sz3[1] - mm));
                p.out[g * 2 + t] = sz3[t] - lse;
            }
            __syncthreads();
        }
    } break;
    }
}

// ---------------------------------------------------------------------------
// cooperative mega-kernel + per-phase fallback
// ---------------------------------------------------------------------------
__global__ __launch_bounds__(256, 4) void mega_all(Params p) {
    __shared__ __align__(16) char smem[SMEM_BYTES];
    cg::grid_group grid = cg::this_grid();
    for (int ph = 0; ph < N_PHASES; ++ph) {
        run_phase(p, ph, smem);
        if (ph != N_PHASES - 1) grid.sync();
    }
}

__global__ __launch_bounds__(256, 4) void mega_one(Params p, int ph) {
    __shared__ __align__(16) char smem[SMEM_BYTES];
    run_phase(p, ph, smem);
}

// ---------------------------------------------------------------------------
// launch
// ---------------------------------------------------------------------------
extern "C" void kernel_launch(void* const* d_in, const int* in_sizes, int n_in,
                              void* d_out, int out_size, void* d_ws, size_t ws_size,
                              hipStream_t stream) {
    Params p;
    p.x = (const float*)d_in[0]; p.ei = (const int*)d_in[1]; p.batch = (const int*)d_in[2];
    p.w_in = (const float*)d_in[3]; p.b_in = (const float*)d_in[4]; p.bn_in = (const float*)d_in[5];
    p.g1_wl = (const float*)d_in[6]; p.g1_bl = (const float*)d_in[7];
    p.g1_wr = (const float*)d_in[8]; p.g1_br = (const float*)d_in[9];
    p.g1_att = (const float*)d_in[10]; p.g1_bias = (const float*)d_in[11]; p.bn1 = (const float*)d_in[12];
    p.g2_wl = (const float*)d_in[13]; p.g2_bl = (const float*)d_in[14];
    p.g2_wr = (const float*)d_in[15]; p.g2_br = (const float*)d_in[16];
    p.g2_att = (const float*)d_in[17]; p.g2_bias = (const float*)d_in[18]; p.bn2 = (const float*)d_in[19];
    p.g3_wl = (const float*)d_in[20]; p.g3_bl = (const float*)d_in[21];
    p.g3_wr = (const float*)d_in[22]; p.g3_br = (const float*)d_in[23];
    p.g3_att = (const float*)d_in[24]; p.g3_bias = (const float*)d_in[25]; p.bn3 = (const float*)d_in[26];
    p.c_w1 = (const float*)d_in[27]; p.c_b1 = (const float*)d_in[28]; p.c_bn = (const float*)d_in[29];
    p.c_w2 = (const float*)d_in[30]; p.c_b2 = (const float*)d_in[31];
    p.c_w3 = (const float*)d_in[32]; p.c_b3 = (const float*)d_in[33];
    p.out = (float*)d_out;

    // workspace layout
    const size_t NHC = (size_t)N_NODES * 256;
    p.a16  = (_Float16*)d_ws;
    p.xl16 = p.a16 + NHC;
    p.xr16 = p.xl16 + NHC;
    _Float16* wt = p.xr16 + NHC;
    p.wt1l = wt;            p.wt1r = wt + 16384;
    p.wt2l = wt + 32768;    p.wt2r = wt + 98304;
    p.wt3l = wt + 163840;   p.wt3r = wt + 196608;
    float* fbase = (float*)(wt + 262144);
    p.bufD = fbase;
    int* iw = (int*)(p.bufD + (size_t)N_NODES * 128);
    p.deg = iw;             p.cnt = iw + 30000;
    p.slocal = iw + 60000;  p.bsums = iw + 90000;
    p.row_start = iw + 90128;
    p.esrc = iw + 120129;
    p.gdeg = iw + 390129;   p.gstart = iw + 390429;

    // one-time host queries (first call is the uncaptured correctness call)
    static int coop = -1;
    static int gridN = 512;
    if (coop < 0) {
        int v = 0;
        hipDeviceGetAttribute(&v, hipDeviceAttributeCooperativeLaunch, 0);
        int nb = 0;
        hipOccupancyMaxActiveBlocksPerMultiprocessor(&nb, mega_all, 256, 0);
        if (nb < 1) nb = 1;
        long g = (long)nb * 256;                // 256 CUs on MI355X
        gridN = (int)(g > 1024 ? 1024 : g);
        coop = (v && gridN >= 128) ? 1 : 0;
    }

    if (coop) {
        void* args[] = { (void*)&p };
        hipError_t rc = hipLaunchCooperativeKernel(mega_all, dim3(gridN), dim3(256),
                                                   args, 0, stream);
        if (rc == hipSuccess) return;
    }
    // fallback: same phases as plain sequential launches
    for (int ph = 0; ph < N_PHASES; ++ph)
        mega_one<<<1024, 256, 0, stream>>>(p, ph);
}

// Round 9
// 412.952 us; speedup vs baseline: 3.2379x; 3.2379x over previous
//
#include <hip/hip_runtime.h>
#include <math.h>

#define N_NODES  30000
#define N_EDGES  240000
#define E_TOT    270000   // N_EDGES + N_NODES self loops
#define N_GRAPHS 300
#define NCH      118      // cdiv(N_NODES, 256)

typedef _Float16 half8 __attribute__((ext_vector_type(8)));
typedef _Float16 half4 __attribute__((ext_vector_type(4)));
typedef _Float16 half2v __attribute__((ext_vector_type(2)));
typedef float float4v __attribute__((ext_vector_type(4)));

static inline int cdiv(int a, int b) { return (a + b - 1) / b; }

// ---------------------------------------------------------------------------
// K1: zero counters + all weight transposes (f32 [K][CO] -> f16 [CO][K])
// ---------------------------------------------------------------------------
__device__ inline void wp_dev(const float* __restrict__ W, _Float16* __restrict__ Wt,
                              int K, int CO, int gtid, int T) {
    int tot = K * CO;
    for (int i = gtid; i < tot; i += T) {
        int k = i / CO, c = i - k * CO;
        Wt[(size_t)c * K + k] = (_Float16)W[i];
    }
}

__global__ void init_wprep(int* __restrict__ deg_cnt, int* __restrict__ gdeg,
                           const float* __restrict__ w1l, const float* __restrict__ w1r,
                           const float* __restrict__ w2l, const float* __restrict__ w2r,
                           const float* __restrict__ w3l, const float* __restrict__ w3r,
                           _Float16* __restrict__ t1l, _Float16* __restrict__ t1r,
                           _Float16* __restrict__ t2l, _Float16* __restrict__ t2r,
                           _Float16* __restrict__ t3l, _Float16* __restrict__ t3r) {
    int gtid = blockIdx.x * blockDim.x + threadIdx.x;
    int T = gridDim.x * blockDim.x;
    for (int i = gtid; i < 60000; i += T) deg_cnt[i] = 0;   // deg + cnt contiguous
    for (int i = gtid; i < N_GRAPHS; i += T) gdeg[i] = 0;
    wp_dev(w1l, t1l, 64, 256, gtid, T);
    wp_dev(w1r, t1r, 64, 256, gtid, T);
    wp_dev(w2l, t2l, 256, 256, gtid, T);
    wp_dev(w2r, t2r, 256, 256, gtid, T);
    wp_dev(w3l, t3l, 256, 128, gtid, T);
    wp_dev(w3r, t3r, 256, 128, gtid, T);
}

// ---------------------------------------------------------------------------
// K2: degree + graph histograms AND input layer (K=5 wave-shuffle GEMM,
// bn+relu, f16 out). The two parts touch disjoint data — no barrier needed.
// ---------------------------------------------------------------------------
__global__ void hist_input(const int* __restrict__ ei, const int* __restrict__ batch,
                           int* __restrict__ deg, int* __restrict__ gdeg,
                           const float* __restrict__ x, const float* __restrict__ w_in,
                           const float* __restrict__ b_in, const float* __restrict__ bn_in,
                           _Float16* __restrict__ a16) {
    int gtid = blockIdx.x * blockDim.x + threadIdx.x;
    int T = gridDim.x * blockDim.x;
    for (int e = gtid; e < E_TOT; e += T) {
        int d = (e < N_EDGES) ? ei[N_EDGES + e] : e - N_EDGES;
        atomicAdd(&deg[d], 1);
    }
    for (int i = gtid; i < N_NODES; i += T) atomicAdd(&gdeg[batch[i]], 1);

    int lane = threadIdx.x & 63;
    int wv = blockIdx.x * (blockDim.x >> 6) + (threadIdx.x >> 6);
    int NW = gridDim.x * (blockDim.x >> 6);
    float g = bn_in[lane], be = bn_in[64 + lane];
    float m = bn_in[128 + lane], va = bn_in[192 + lane];
    float rs = rsqrtf(va + 1e-5f);
    float wcol[5];
#pragma unroll
    for (int ci = 0; ci < 5; ++ci) wcol[ci] = w_in[ci * 64 + lane];
    float bb = b_in[lane];
    for (int n = wv; n < N_NODES; n += NW) {
        float xv = (lane < 5) ? x[n * 5 + lane] : 0.f;
        float acc = bb;
#pragma unroll
        for (int ci = 0; ci < 5; ++ci)
            acc = fmaf(__shfl(xv, ci, 64), wcol[ci], acc);
        acc = g * (acc - m) * rs + be;
        a16[(size_t)n * 64 + lane] = (_Float16)fmaxf(acc, 0.f);
    }
}

// ---------------------------------------------------------------------------
// K3: one-launch scan. Block b sums deg[0 .. b*256) directly (L2-resident),
// adds local chunk scan -> row_start. Block 0 also pair-scans gstart.
// No cross-block communication.
// ---------------------------------------------------------------------------
__global__ __launch_bounds__(256)
void scan_all(const int* __restrict__ deg, const int* __restrict__ gdeg,
              int* __restrict__ row_start, int* __restrict__ gstart) {
    __shared__ int red[256];
    __shared__ int s[256];
    const int b = blockIdx.x, t = threadIdx.x;
    // prefix base: sum of all chunks before b
    int pre = 0;
    for (int i = t; i < b * 256; i += 256) pre += deg[i];
    red[t] = pre;
    __syncthreads();
    for (int off = 128; off; off >>= 1) {
        if (t < off) red[t] += red[t + off];
        __syncthreads();
    }
    int base = red[0];
    // local chunk exclusive scan
    int gid = b * 256 + t;
    int v = (gid < N_NODES) ? deg[gid] : 0;
    s[t] = v;
    __syncthreads();
    for (int off = 1; off < 256; off <<= 1) {
        int u = (t >= off) ? s[t - off] : 0;
        __syncthreads();
        s[t] += u;
        __syncthreads();
    }
    if (gid < N_NODES) row_start[gid] = base + s[t] - v;
    if (b == 0 && t == 0) row_start[N_NODES] = E_TOT;
    // graph-start scan (block 0 only; branch is block-uniform)
    if (b == 0) {
        __syncthreads();
        int i0 = 2 * t, i1 = 2 * t + 1;
        int a0 = (i0 < N_GRAPHS) ? gdeg[i0] : 0;
        int a1 = (i1 < N_GRAPHS) ? gdeg[i1] : 0;
        int ps = a0 + a1;
        s[t] = ps;
        __syncthreads();
        for (int off = 1; off < 256; off <<= 1) {
            int u = (t >= off) ? s[t - off] : 0;
            __syncthreads();
            s[t] += u;
            __syncthreads();
        }
        int excl = s[t] - ps;
        if (i0 < N_GRAPHS) gstart[i0] = excl;
        if (i1 < N_GRAPHS) gstart[i1] = excl + a0;
        if (t == 0) gstart[N_GRAPHS] = N_NODES;
    }
}

// ---------------------------------------------------------------------------
// K4: CSR scatter
// ---------------------------------------------------------------------------
__global__ void csr_scatter(const int* __restrict__ ei, const int* __restrict__ row_start,
                            int* __restrict__ cnt, int* __restrict__ esrc) {
    int e = blockIdx.x * blockDim.x + threadIdx.x;
    if (e >= E_TOT) return;
    int s, d;
    if (e < N_EDGES) { s = ei[e]; d = ei[N_EDGES + e]; }
    else             { s = e - N_EDGES; d = s; }
    int slot = row_start[d] + atomicAdd(&cnt[d], 1);
    esrc[slot] = s;
}

// ---------------------------------------------------------------------------
// MFMA f16 pair GEMM (fp32 accumulate) — unchanged from Round 7
// ---------------------------------------------------------------------------
template<int K, int COUT>
__global__ __launch_bounds__(256, 3)
void gemm_mfma(const _Float16* __restrict__ A,
               const _Float16* __restrict__ Wtl, const float* __restrict__ bl,
               const _Float16* __restrict__ Wtr, const float* __restrict__ br,
               _Float16* __restrict__ outl, _Float16* __restrict__ outr, int N) {
    constexpr int BM = 128, BN = 128, BK = 64;
    constexpr int LDK = BK + 8;
    __shared__ _Float16 As[BM][LDK];
    __shared__ _Float16 Bs[BN][LDK];
    const int tid  = threadIdx.x;
    const int wave = tid >> 6;
    const int lane = tid & 63;
    const int l15  = lane & 15;
    const int lq   = lane >> 4;
    const int n0   = blockIdx.x * BM;
    constexpr int CSL = COUT / BN > 0 ? COUT / BN : 1;
    const int sel  = blockIdx.y / CSL;
    const int col0 = (blockIdx.y % CSL) * BN;
    const _Float16* Wt = sel ? Wtr : Wtl;
    const float* bias  = sel ? br : bl;
    _Float16* out      = sel ? outr : outl;

    float4v acc[2][8];
#pragma unroll
    for (int mi = 0; mi < 2; ++mi)
#pragma unroll
        for (int nt = 0; nt < 8; ++nt)
#pragma unroll
            for (int r = 0; r < 4; ++r) acc[mi][nt][r] = 0.f;

    for (int kt = 0; kt < K; kt += BK) {
#pragma unroll
        for (int p = 0; p < 4; ++p) {
            int idx = p * 256 + tid;
            int row = idx >> 3;
            int ch  = (idx & 7) * 8;
            int gn  = n0 + row;
            half8 v = {};
            if (gn < N) v = *(const half8*)(A + (size_t)gn * K + kt + ch);
            *(half8*)(&As[row][ch]) = v;
        }
#pragma unroll
        for (int p = 0; p < 4; ++p) {
            int idx = p * 256 + tid;
            int row = idx >> 3;
            int ch  = (idx & 7) * 8;
            half8 v = *(const half8*)(Wt + (size_t)(col0 + row) * K + kt + ch);
            *(half8*)(&Bs[row][ch]) = v;
        }
        __syncthreads();
#pragma unroll
        for (int kk = 0; kk < BK; kk += 32) {
            half8 af0 = *(const half8*)(&As[wave * 32 + l15][kk + lq * 8]);
            half8 af1 = *(const half8*)(&As[wave * 32 + 16 + l15][kk + lq * 8]);
#pragma unroll
            for (int nt = 0; nt < 8; ++nt) {
                half8 bf = *(const half8*)(&Bs[nt * 16 + l15][kk + lq * 8]);
                acc[0][nt] = __builtin_amdgcn_mfma_f32_16x16x32_f16(af0, bf, acc[0][nt], 0, 0, 0);
                acc[1][nt] = __builtin_amdgcn_mfma_f32_16x16x32_f16(af1, bf, acc[1][nt], 0, 0, 0);
            }
        }
        __syncthreads();
    }
#pragma unroll
    for (int mi = 0; mi < 2; ++mi)
#pragma unroll
        for (int nt = 0; nt < 8; ++nt) {
            int col = col0 + nt * 16 + l15;
            float bv = bias[col];
#pragma unroll
            for (int r = 0; r < 4; ++r) {
                int row = n0 + wave * 32 + mi * 16 + lq * 4 + r;
                if (row < N)
                    out[(size_t)row * COUT + col] = (_Float16)(acc[mi][nt][r] + bv);
            }
        }
}

// ---------------------------------------------------------------------------
// fused GATv2 gather, 4-edge-unrolled online softmax — unchanged from Round 7
// ---------------------------------------------------------------------------
template<int H, int C, typename TOUT>
__global__ __launch_bounds__(256)
void gat_gather(const _Float16* __restrict__ xl, const _Float16* __restrict__ xr,
                const int* __restrict__ row_start, const int* __restrict__ esrc,
                const float* __restrict__ att, const float* __restrict__ gbias,
                const float* __restrict__ bnp, TOUT* __restrict__ out) {
    constexpr int HC    = H * C;
    constexpr int PER   = HC / 64;
    constexpr int GROUP = 64 / H;
    int node = (blockIdx.x * blockDim.x + threadIdx.x) >> 6;
    int lane = threadIdx.x & 63;
    if (node >= N_NODES) return;
    const int base = lane * PER;

    float rr[PER], av[PER], acc[PER];
    if constexpr (PER == 4) {
        half4 rv = *(const half4*)(xr + (size_t)node * HC + base);
#pragma unroll
        for (int k = 0; k < PER; ++k) rr[k] = (float)rv[k];
        *(float4*)av = *(const float4*)(att + base);
    } else {
        half2v rv = *(const half2v*)(xr + (size_t)node * HC + base);
#pragma unroll
        for (int k = 0; k < PER; ++k) rr[k] = (float)rv[k];
        *(float2*)av = *(const float2*)(att + base);
    }
#pragma unroll
    for (int k = 0; k < PER; ++k) acc[k] = 0.f;

    float m = -INFINITY, l = 0.f;
    const int j0 = row_start[node], j1 = row_start[node + 1];
    for (int jc = j0; jc < j1; jc += 64) {
        int nedge = min(64, j1 - jc);
        int ev = (jc + lane < j1) ? esrc[jc + lane] : 0;
        int jj = 0;
        for (; jj + 4 <= nedge; jj += 4) {
            int s[4];
#pragma unroll
            for (int u = 0; u < 4; ++u) s[u] = __shfl(ev, jj + u, 64);
            float xs[4][PER];
#pragma unroll
            for (int u = 0; u < 4; ++u) {
                if constexpr (PER == 4) {
                    half4 xv = *(const half4*)(xl + (size_t)s[u] * HC + base);
#pragma unroll
                    for (int k = 0; k < PER; ++k) xs[u][k] = (float)xv[k];
                } else {
                    half2v xv = *(const half2v*)(xl + (size_t)s[u] * HC + base);
#pragma unroll
                    for (int k = 0; k < PER; ++k) xs[u][k] = (float)xv[k];
                }
            }
            float pz[4];
#pragma unroll
            for (int u = 0; u < 4; ++u) {
                float pp = 0.f;
#pragma unroll
                for (int k = 0; k < PER; ++k) {
                    float v = xs[u][k] + rr[k];
                    v = (v > 0.f) ? v : 0.2f * v;
                    pp = fmaf(v, av[k], pp);
                }
                pz[u] = pp;
            }
#pragma unroll
            for (int off = GROUP / 2; off; off >>= 1) {
#pragma unroll
                for (int u = 0; u < 4; ++u) pz[u] += __shfl_xor(pz[u], off, 64);
            }
            float mx = fmaxf(fmaxf(pz[0], pz[1]), fmaxf(pz[2], pz[3]));
            float mn = fmaxf(m, mx);
            float scale = __expf(m - mn);
            float w[4];
#pragma unroll
            for (int u = 0; u < 4; ++u) w[u] = __expf(pz[u] - mn);
            l = fmaf(l, scale, (w[0] + w[1]) + (w[2] + w[3]));
#pragma unroll
            for (int k = 0; k < PER; ++k) {
                float tt = fmaf(w[0], xs[0][k],
                           fmaf(w[1], xs[1][k],
                           fmaf(w[2], xs[2][k], w[3] * xs[3][k])));
                acc[k] = fmaf(acc[k], scale, tt);
            }
            m = mn;
        }
        for (; jj < nedge; ++jj) {
            int s = __shfl(ev, jj, 64);
            float xls[PER];
            if constexpr (PER == 4) {
                half4 xv = *(const half4*)(xl + (size_t)s * HC + base);
#pragma unroll
                for (int k = 0; k < PER; ++k) xls[k] = (float)xv[k];
            } else {
                half2v xv = *(const half2v*)(xl + (size_t)s * HC + base);
#pragma unroll
                for (int k = 0; k < PER; ++k) xls[k] = (float)xv[k];
            }
            float pp = 0.f;
#pragma unroll
            for (int k = 0; k < PER; ++k) {
                float v = xls[k] + rr[k];
                v = (v > 0.f) ? v : 0.2f * v;
                pp = fmaf(v, av[k], pp);
            }
#pragma unroll
            for (int off = GROUP / 2; off; off >>= 1) pp += __shfl_xor(pp, off, 64);
            float mn    = fmaxf(m, pp);
            float scale = __expf(m - mn);
            float w     = __expf(pp - mn);
            l = fmaf(l, scale, w);
#pragma unroll
            for (int k = 0; k < PER; ++k) acc[k] = fmaf(acc[k], scale, w * xls[k]);
            m = mn;
        }
    }
    float inv = 1.f / (l + 1e-16f);
    float o[PER];
#pragma unroll
    for (int k = 0; k < PER; ++k) {
        float v = fmaf(acc[k], inv, gbias[base + k]);
        float g  = bnp[base + k], be = bnp[HC + base + k];
        float mm = bnp[2 * HC + base + k], va = bnp[3 * HC + base + k];
        v = g * (v - mm) * rsqrtf(va + 1e-5f) + be;
        o[k] = (v > 0.f) ? v : (__expf(v) - 1.f);
    }
    if constexpr (sizeof(TOUT) == 2) {
        if constexpr (PER == 4) {
            half4 ov;
#pragma unroll
            for (int k = 0; k < PER; ++k) ov[k] = (_Float16)o[k];
            *(half4*)((_Float16*)out + (size_t)node * HC + base) = ov;
        } else {
            half2v ov;
#pragma unroll
            for (int k = 0; k < PER; ++k) ov[k] = (_Float16)o[k];
            *(half2v*)((_Float16*)out + (size_t)node * HC + base) = ov;
        }
    } else {
        if constexpr (PER == 4)
            *(float4*)((float*)out + (size_t)node * HC + base) = *(float4*)o;
        else
            *(float2*)((float*)out + (size_t)node * HC + base) = *(float2*)o;
    }
}

// ---------------------------------------------------------------------------
// K11: fused pooling + classifier, one block (128 threads) per graph
// ---------------------------------------------------------------------------
__global__ void pool_cls(const float* __restrict__ h, const int* __restrict__ gstart,
                         const float* __restrict__ w1, const float* __restrict__ b1,
                         const float* __restrict__ bnp,
                         const float* __restrict__ w2, const float* __restrict__ b2,
                         const float* __restrict__ w3, const float* __restrict__ b3,
                         float* __restrict__ out) {
    __shared__ float sg[256];
    __shared__ float sz1[128];
    __shared__ float sz2[64];
    __shared__ float sz3[2];
    int g = blockIdx.x, t = threadIdx.x;
    int a = gstart[g], b = gstart[g + 1];
    float sum = 0.f, mx = -INFINITY;
    for (int i = a; i < b; ++i) {
        float v = h[(size_t)i * 128 + t];
        sum += v;
        mx = fmaxf(mx, v);
    }
    sg[t]       = sum / fmaxf((float)(b - a), 1.f);
    sg[128 + t] = (b > a) ? mx : 0.f;
    __syncthreads();
    float acc = b1[t];
    for (int i = 0; i < 256; ++i) acc += sg[i] * w1[i * 128 + t];
    float ga = bnp[t], be = bnp[128 + t], m = bnp[256 + t], va = bnp[384 + t];
    acc = ga * (acc - m) * rsqrtf(va + 1e-5f) + be;
    sz1[t] = fmaxf(acc, 0.f);
    __syncthreads();
    if (t < 64) {
        float a2 = b2[t];
        for (int i = 0; i < 128; ++i) a2 += sz1[i] * w2[i * 64 + t];
        sz2[t] = fmaxf(a2, 0.f);
    }
    __syncthreads();
    if (t < 2) {
        float a3 = b3[t];
        for (int i = 0; i < 64; ++i) a3 += sz2[i] * w3[i * 2 + t];
        sz3[t] = a3;
    }
    __syncthreads();
    if (t < 2) {
        float mm = fmaxf(sz3[0], sz3[1]);
        float lse = mm + logf(expf(sz3[0] - mm) + expf(sz3[1] - mm));
        out[g * 2 + t] = sz3[t] - lse;
    }
}

// ---------------------------------------------------------------------------
// launch: 11 kernels total
// ---------------------------------------------------------------------------
extern "C" void kernel_launch(void* const* d_in, const int* in_sizes, int n_in,
                              void* d_out, int out_size, void* d_ws, size_t ws_size,
                              hipStream_t stream) {
    const float* x       = (const float*)d_in[0];
    const int*   ei      = (const int*)d_in[1];
    const int*   batch   = (const int*)d_in[2];
    const float* w_in    = (const float*)d_in[3];
    const float* b_in    = (const float*)d_in[4];
    const float* bn_in   = (const float*)d_in[5];
    const float* g1_wl   = (const float*)d_in[6];
    const float* g1_bl   = (const float*)d_in[7];
    const float* g1_wr   = (const float*)d_in[8];
    const float* g1_br   = (const float*)d_in[9];
    const float* g1_att  = (const float*)d_in[10];
    const float* g1_bias = (const float*)d_in[11];
    const float* bn1     = (const float*)d_in[12];
    const float* g2_wl   = (const float*)d_in[13];
    const float* g2_bl   = (const float*)d_in[14];
    const float* g2_wr   = (const float*)d_in[15];
    const float* g2_br   = (const float*)d_in[16];
    const float* g2_att  = (const float*)d_in[17];
    const float* g2_bias = (const float*)d_in[18];
    const float* bn2     = (const float*)d_in[19];
    const float* g3_wl   = (const float*)d_in[20];
    const float* g3_bl   = (const float*)d_in[21];
    const float* g3_wr   = (const float*)d_in[22];
    const float* g3_br   = (const float*)d_in[23];
    const float* g3_att  = (const float*)d_in[24];
    const float* g3_bias = (const float*)d_in[25];
    const float* bn3     = (const float*)d_in[26];
    const float* c_w1    = (const float*)d_in[27];
    const float* c_b1    = (const float*)d_in[28];
    const float* c_bn    = (const float*)d_in[29];
    const float* c_w2    = (const float*)d_in[30];
    const float* c_b2    = (const float*)d_in[31];
    const float* c_w3    = (const float*)d_in[32];
    const float* c_b3    = (const float*)d_in[33];
    float* out = (float*)d_out;

    // ---- workspace layout (same as Round 7)
    const size_t NHC = (size_t)N_NODES * 256;
    _Float16* a16  = (_Float16*)d_ws;
    _Float16* xl16 = a16 + NHC;
    _Float16* xr16 = xl16 + NHC;
    _Float16* wt = xr16 + NHC;
    _Float16* wt1l = wt;            _Float16* wt1r = wt + 16384;
    _Float16* wt2l = wt + 32768;    _Float16* wt2r = wt + 98304;
    _Float16* wt3l = wt + 163840;   _Float16* wt3r = wt + 196608;
    float* fbase = (float*)(wt + 262144);
    float* bufD = fbase;
    float* gbuf = bufD + (size_t)N_NODES * 128;   // (unused scratch region ok)
    int* iw = (int*)(gbuf + N_GRAPHS * 256);
    int* deg       = iw;            int* cnt    = iw + 30000;
    int* slocal    = iw + 60000;    int* bsums  = iw + 90000;   // (legacy, unused)
    int* row_start = iw + 90128;
    int* esrc      = iw + 120129;
    int* gdeg      = iw + 390129;   int* gstart = iw + 390429;
    (void)slocal; (void)bsums;

    const int BT = 256;
    const int NT128 = cdiv(N_NODES, 128);      // 235

    // K1: init + weight prep
    init_wprep<<<512, BT, 0, stream>>>(deg, gdeg, g1_wl, g1_wr, g2_wl, g2_wr,
                                       g3_wl, g3_wr, wt1l, wt1r, wt2l, wt2r, wt3l, wt3r);
    // K2: histograms + input layer
    hist_input<<<1024, BT, 0, stream>>>(ei, batch, deg, gdeg, x, w_in, b_in, bn_in, a16);
    // K3: full scan (row_start + gstart) in one launch
    scan_all<<<NCH, 256, 0, stream>>>(deg, gdeg, row_start, gstart);
    // K4: CSR scatter
    csr_scatter<<<cdiv(E_TOT, BT), BT, 0, stream>>>(ei, row_start, cnt, esrc);

    // K5/K6: GAT layer 1
    gemm_mfma<64, 256><<<dim3(NT128, 4), 256, 0, stream>>>(
        a16, wt1l, g1_bl, wt1r, g1_br, xl16, xr16, N_NODES);
    gat_gather<4, 64, _Float16><<<cdiv(N_NODES * 64, BT), BT, 0, stream>>>(
        xl16, xr16, row_start, esrc, g1_att, g1_bias, bn1, a16);

    // K7/K8: GAT layer 2
    gemm_mfma<256, 256><<<dim3(NT128, 4), 256, 0, stream>>>(
        a16, wt2l, g2_bl, wt2r, g2_br, xl16, xr16, N_NODES);
    gat_gather<4, 64, _Float16><<<cdiv(N_NODES * 64, BT), BT, 0, stream>>>(
        xl16, xr16, row_start, esrc, g2_att, g2_bias, bn2, a16);

    // K9/K10: GAT layer 3 (gather emits f32 for pooling)
    gemm_mfma<256, 128><<<dim3(NT128, 2), 256, 0, stream>>>(
        a16, wt3l, g3_bl, wt3r, g3_br, xl16, xr16, N_NODES);
    gat_gather<1, 128, float><<<cdiv(N_NODES * 64, BT), BT, 0, stream>>>(
        xl16, xr16, row_start, esrc, g3_att, g3_bias, bn3, bufD);

    // K11: fused pooling + classifier
    pool_cls<<<N_GRAPHS, 128, 0, stream>>>(bufD, gstart, c_w1, c_b1, c_bn,
                                           c_w2, c_b2, c_w3, c_b3, out);
}

// Round 10
// 385.598 us; speedup vs baseline: 3.4676x; 1.0709x over previous
//
#include <hip/hip_runtime.h>
#include <math.h>

#define N_NODES  30000
#define N_EDGES  240000
#define E_TOT    270000   // N_EDGES + N_NODES self loops
#define N_GRAPHS 300
#define NCH      118      // cdiv(N_NODES, 256)

typedef _Float16 half8 __attribute__((ext_vector_type(8)));
typedef _Float16 half4 __attribute__((ext_vector_type(4)));
typedef _Float16 half2v __attribute__((ext_vector_type(2)));
typedef float float4v __attribute__((ext_vector_type(4)));

static inline int cdiv(int a, int b) { return (a + b - 1) / b; }

// ---------------------------------------------------------------------------
// K1: zero counters + all weight transposes (f32 [K][CO] -> f16 [CO][K])
// ---------------------------------------------------------------------------
__device__ inline void wp_dev(const float* __restrict__ W, _Float16* __restrict__ Wt,
                              int K, int CO, int gtid, int T) {
    int tot = K * CO;
    for (int i = gtid; i < tot; i += T) {
        int k = i / CO, c = i - k * CO;
        Wt[(size_t)c * K + k] = (_Float16)W[i];
    }
}

__global__ void init_wprep(int* __restrict__ deg_cnt,
                           const float* __restrict__ w1l, const float* __restrict__ w1r,
                           const float* __restrict__ w2l, const float* __restrict__ w2r,
                           const float* __restrict__ w3l, const float* __restrict__ w3r,
                           _Float16* __restrict__ t1l, _Float16* __restrict__ t1r,
                           _Float16* __restrict__ t2l, _Float16* __restrict__ t2r,
                           _Float16* __restrict__ t3l, _Float16* __restrict__ t3r) {
    int gtid = blockIdx.x * blockDim.x + threadIdx.x;
    int T = gridDim.x * blockDim.x;
    for (int i = gtid; i < 60000; i += T) deg_cnt[i] = 0;   // deg + cnt contiguous
    wp_dev(w1l, t1l, 64, 256, gtid, T);
    wp_dev(w1r, t1r, 64, 256, gtid, T);
    wp_dev(w2l, t2l, 256, 256, gtid, T);
    wp_dev(w2r, t2r, 256, 256, gtid, T);
    wp_dev(w3l, t3l, 256, 128, gtid, T);
    wp_dev(w3r, t3r, 256, 128, gtid, T);
}

// ---------------------------------------------------------------------------
// K2: degree histogram (random dst -> low contention) + input layer
// (K=5 wave-shuffle GEMM, bn+relu, f16 out). NO sorted-batch histogram:
// 30K same-address atomics on 300 counters serialized ~45us in Round 9.
// ---------------------------------------------------------------------------
__global__ void hist_input(const int* __restrict__ ei,
                           int* __restrict__ deg,
                           const float* __restrict__ x, const float* __restrict__ w_in,
                           const float* __restrict__ b_in, const float* __restrict__ bn_in,
                           _Float16* __restrict__ a16) {
    int gtid = blockIdx.x * blockDim.x + threadIdx.x;
    int T = gridDim.x * blockDim.x;
    for (int e = gtid; e < E_TOT; e += T) {
        int d = (e < N_EDGES) ? ei[N_EDGES + e] : e - N_EDGES;
        atomicAdd(&deg[d], 1);
    }
    int lane = threadIdx.x & 63;
    int wv = blockIdx.x * (blockDim.x >> 6) + (threadIdx.x >> 6);
    int NW = gridDim.x * (blockDim.x >> 6);
    float g = bn_in[lane], be = bn_in[64 + lane];
    float m = bn_in[128 + lane], va = bn_in[192 + lane];
    float rs = rsqrtf(va + 1e-5f);
    float wcol[5];
#pragma unroll
    for (int ci = 0; ci < 5; ++ci) wcol[ci] = w_in[ci * 64 + lane];
    float bb = b_in[lane];
    for (int n = wv; n < N_NODES; n += NW) {
        float xv = (lane < 5) ? x[n * 5 + lane] : 0.f;
        float acc = bb;
#pragma unroll
        for (int ci = 0; ci < 5; ++ci)
            acc = fmaf(__shfl(xv, ci, 64), wcol[ci], acc);
        acc = g * (acc - m) * rs + be;
        a16[(size_t)n * 64 + lane] = (_Float16)fmaxf(acc, 0.f);
    }
}

// ---------------------------------------------------------------------------
// K3: one-launch scan. Block b sums deg[0 .. b*256) directly (L2-resident),
// adds local chunk scan -> row_start. Block 0 also binary-searches gstart
// (batch is sorted): gstart[g] = lower_bound(batch, g). No atomics.
// ---------------------------------------------------------------------------
__global__ __launch_bounds__(256)
void scan_all(const int* __restrict__ deg, const int* __restrict__ batch,
              int* __restrict__ row_start, int* __restrict__ gstart) {
    __shared__ int red[256];
    __shared__ int s[256];
    const int b = blockIdx.x, t = threadIdx.x;
    int pre = 0;
    for (int i = t; i < b * 256; i += 256) pre += deg[i];
    red[t] = pre;
    __syncthreads();
    for (int off = 128; off; off >>= 1) {
        if (t < off) red[t] += red[t + off];
        __syncthreads();
    }
    int base = red[0];
    int gid = b * 256 + t;
    int v = (gid < N_NODES) ? deg[gid] : 0;
    s[t] = v;
    __syncthreads();
    for (int off = 1; off < 256; off <<= 1) {
        int u = (t >= off) ? s[t - off] : 0;
        __syncthreads();
        s[t] += u;
        __syncthreads();
    }
    if (gid < N_NODES) row_start[gid] = base + s[t] - v;
    if (b == 0 && t == 0) row_start[N_NODES] = E_TOT;
    if (b == 0) {
        for (int g = t; g <= N_GRAPHS; g += 256) {
            int lo = 0, hi = N_NODES;
            while (lo < hi) {
                int mid = (lo + hi) >> 1;
                if (batch[mid] < g) lo = mid + 1;
                else                hi = mid;
            }
            gstart[g] = lo;
        }
    }
}

// ---------------------------------------------------------------------------
// MFMA f16 pair GEMM (fp32 accumulate). SCAT=1 adds a blockIdx.y slice that
// performs the CSR scatter (independent work, hides under the GEMM).
// ---------------------------------------------------------------------------
template<int K, int COUT, int SCAT>
__global__ __launch_bounds__(256, 3)
void gemm_mfma(const _Float16* __restrict__ A,
               const _Float16* __restrict__ Wtl, const float* __restrict__ bl,
               const _Float16* __restrict__ Wtr, const float* __restrict__ br,
               _Float16* __restrict__ outl, _Float16* __restrict__ outr,
               const int* __restrict__ ei, const int* __restrict__ row_start,
               int* __restrict__ cnt, int* __restrict__ esrc, int N) {
    constexpr int BM = 128, BN = 128, BK = 64;
    constexpr int LDK = BK + 8;
    constexpr int CSL = COUT / BN > 0 ? COUT / BN : 1;
    if (SCAT && blockIdx.y == 2 * CSL) {       // scatter slice
        int gtid = blockIdx.x * blockDim.x + threadIdx.x;
        int T = gridDim.x * blockDim.x;
        for (int e = gtid; e < E_TOT; e += T) {
            int s, d;
            if (e < N_EDGES) { s = ei[e]; d = ei[N_EDGES + e]; }
            else             { s = e - N_EDGES; d = s; }
            int slot = row_start[d] + atomicAdd(&cnt[d], 1);
            esrc[slot] = s;
        }
        return;
    }
    __shared__ _Float16 As[BM][LDK];
    __shared__ _Float16 Bs[BN][LDK];
    const int tid  = threadIdx.x;
    const int wave = tid >> 6;
    const int lane = tid & 63;
    const int l15  = lane & 15;
    const int lq   = lane >> 4;
    const int n0   = blockIdx.x * BM;
    const int sel  = blockIdx.y / CSL;
    const int col0 = (blockIdx.y % CSL) * BN;
    const _Float16* Wt = sel ? Wtr : Wtl;
    const float* bias  = sel ? br : bl;
    _Float16* out      = sel ? outr : outl;

    float4v acc[2][8];
#pragma unroll
    for (int mi = 0; mi < 2; ++mi)
#pragma unroll
        for (int nt = 0; nt < 8; ++nt)
#pragma unroll
            for (int r = 0; r < 4; ++r) acc[mi][nt][r] = 0.f;

    for (int kt = 0; kt < K; kt += BK) {
#pragma unroll
        for (int p = 0; p < 4; ++p) {
            int idx = p * 256 + tid;
            int row = idx >> 3;
            int ch  = (idx & 7) * 8;
            int gn  = n0 + row;
            half8 v = {};
            if (gn < N) v = *(const half8*)(A + (size_t)gn * K + kt + ch);
            *(half8*)(&As[row][ch]) = v;
        }
#pragma unroll
        for (int p = 0; p < 4; ++p) {
            int idx = p * 256 + tid;
            int row = idx >> 3;
            int ch  = (idx & 7) * 8;
            half8 v = *(const half8*)(Wt + (size_t)(col0 + row) * K + kt + ch);
            *(half8*)(&Bs[row][ch]) = v;
        }
        __syncthreads();
#pragma unroll
        for (int kk = 0; kk < BK; kk += 32) {
            half8 af0 = *(const half8*)(&As[wave * 32 + l15][kk + lq * 8]);
            half8 af1 = *(const half8*)(&As[wave * 32 + 16 + l15][kk + lq * 8]);
#pragma unroll
            for (int nt = 0; nt < 8; ++nt) {
                half8 bf = *(const half8*)(&Bs[nt * 16 + l15][kk + lq * 8]);
                acc[0][nt] = __builtin_amdgcn_mfma_f32_16x16x32_f16(af0, bf, acc[0][nt], 0, 0, 0);
                acc[1][nt] = __builtin_amdgcn_mfma_f32_16x16x32_f16(af1, bf, acc[1][nt], 0, 0, 0);
            }
        }
        __syncthreads();
    }
#pragma unroll
    for (int mi = 0; mi < 2; ++mi)
#pragma unroll
        for (int nt = 0; nt < 8; ++nt) {
            int col = col0 + nt * 16 + l15;
            float bv = bias[col];
#pragma unroll
            for (int r = 0; r < 4; ++r) {
                int row = n0 + wave * 32 + mi * 16 + lq * 4 + r;
                if (row < N)
                    out[(size_t)row * COUT + col] = (_Float16)(acc[mi][nt][r] + bv);
            }
        }
}

// ---------------------------------------------------------------------------
// fused GATv2 gather: predicated 4-edge batches (no scalar tail). Invalid
// slots get logit=-inf -> weight 0; index clamped to a valid edge.
// ---------------------------------------------------------------------------
template<int H, int C, typename TOUT>
__global__ __launch_bounds__(256)
void gat_gather(const _Float16* __restrict__ xl, const _Float16* __restrict__ xr,
                const int* __restrict__ row_start, const int* __restrict__ esrc,
                const float* __restrict__ att, const float* __restrict__ gbias,
                const float* __restrict__ bnp, TOUT* __restrict__ out) {
    constexpr int HC    = H * C;
    constexpr int PER   = HC / 64;
    constexpr int GROUP = 64 / H;
    int node = (blockIdx.x * blockDim.x + threadIdx.x) >> 6;
    int lane = threadIdx.x & 63;
    if (node >= N_NODES) return;
    const int base = lane * PER;

    float rr[PER], av[PER], acc[PER];
    if constexpr (PER == 4) {
        half4 rv = *(const half4*)(xr + (size_t)node * HC + base);
#pragma unroll
        for (int k = 0; k < PER; ++k) rr[k] = (float)rv[k];
        *(float4*)av = *(const float4*)(att + base);
    } else {
        half2v rv = *(const half2v*)(xr + (size_t)node * HC + base);
#pragma unroll
        for (int k = 0; k < PER; ++k) rr[k] = (float)rv[k];
        *(float2*)av = *(const float2*)(att + base);
    }
#pragma unroll
    for (int k = 0; k < PER; ++k) acc[k] = 0.f;

    float m = -INFINITY, l = 0.f;
    const int j0 = row_start[node], j1 = row_start[node + 1];
    for (int jc = j0; jc < j1; jc += 64) {
        int nedge = min(64, j1 - jc);
        int ev = (jc + lane < j1) ? esrc[jc + lane] : 0;
        for (int jj = 0; jj < nedge; jj += 4) {
            int s[4];
            bool val[4];
#pragma unroll
            for (int u = 0; u < 4; ++u) {
                int idx = jj + u;
                val[u] = idx < nedge;
                s[u] = __shfl(ev, val[u] ? idx : jj, 64);
            }
            float xs[4][PER];
#pragma unroll
            for (int u = 0; u < 4; ++u) {
                if constexpr (PER == 4) {
                    half4 xv = *(const half4*)(xl + (size_t)s[u] * HC + base);
#pragma unroll
                    for (int k = 0; k < PER; ++k) xs[u][k] = (float)xv[k];
                } else {
                    half2v xv = *(const half2v*)(xl + (size_t)s[u] * HC + base);
#pragma unroll
                    for (int k = 0; k < PER; ++k) xs[u][k] = (float)xv[k];
                }
            }
            float pz[4];
#pragma unroll
            for (int u = 0; u < 4; ++u) {
                float pp = 0.f;
#pragma unroll
                for (int k = 0; k < PER; ++k) {
                    float v = xs[u][k] + rr[k];
                    v = (v > 0.f) ? v : 0.2f * v;
                    pp = fmaf(v, av[k], pp);
                }
                pz[u] = pp;
            }
#pragma unroll
            for (int off = GROUP / 2; off; off >>= 1) {
#pragma unroll
                for (int u = 0; u < 4; ++u) pz[u] += __shfl_xor(pz[u], off, 64);
            }
#pragma unroll
            for (int u = 0; u < 4; ++u) if (!val[u]) pz[u] = -INFINITY;
            float mx = fmaxf(fmaxf(pz[0], pz[1]), fmaxf(pz[2], pz[3]));
            float mn = fmaxf(m, mx);
            float scale = __expf(m - mn);
            float w[4];
#pragma unroll
            for (int u = 0; u < 4; ++u) w[u] = __expf(pz[u] - mn);   // invalid -> 0
            l = fmaf(l, scale, (w[0] + w[1]) + (w[2] + w[3]));
#pragma unroll
            for (int k = 0; k < PER; ++k) {
                float tt = fmaf(w[0], xs[0][k],
                           fmaf(w[1], xs[1][k],
                           fmaf(w[2], xs[2][k], w[3] * xs[3][k])));
                acc[k] = fmaf(acc[k], scale, tt);
            }
            m = mn;
        }
    }
    float inv = 1.f / (l + 1e-16f);
    float o[PER];
#pragma unroll
    for (int k = 0; k < PER; ++k) {
        float v = fmaf(acc[k], inv, gbias[base + k]);
        float g  = bnp[base + k], be = bnp[HC + base + k];
        float mm = bnp[2 * HC + base + k], va = bnp[3 * HC + base + k];
        v = g * (v - mm) * rsqrtf(va + 1e-5f) + be;
        o[k] = (v > 0.f) ? v : (__expf(v) - 1.f);
    }
    if constexpr (sizeof(TOUT) == 2) {
        if constexpr (PER == 4) {
            half4 ov;
#pragma unroll
            for (int k = 0; k < PER; ++k) ov[k] = (_Float16)o[k];
            *(half4*)((_Float16*)out + (size_t)node * HC + base) = ov;
        } else {
            half2v ov;
#pragma unroll
            for (int k = 0; k < PER; ++k) ov[k] = (_Float16)o[k];
            *(half2v*)((_Float16*)out + (size_t)node * HC + base) = ov;
        }
    } else {
        if constexpr (PER == 4)
            *(float4*)((float*)out + (size_t)node * HC + base) = *(float4*)o;
        else
            *(float2*)((float*)out + (size_t)node * HC + base) = *(float2*)o;
    }
}

// ---------------------------------------------------------------------------
// K10: fused pooling + classifier, one block (128 threads) per graph
// ---------------------------------------------------------------------------
__global__ void pool_cls(const float* __restrict__ h, const int* __restrict__ gstart,
                         const float* __restrict__ w1, const float* __restrict__ b1,
                         const float* __restrict__ bnp,
                         const float* __restrict__ w2, const float* __restrict__ b2,
                         const float* __restrict__ w3, const float* __restrict__ b3,
                         float* __restrict__ out) {
    __shared__ float sg[256];
    __shared__ float sz1[128];
    __shared__ float sz2[64];
    __shared__ float sz3[2];
    int g = blockIdx.x, t = threadIdx.x;
    int a = gstart[g], b = gstart[g + 1];
    float sum = 0.f, mx = -INFINITY;
    for (int i = a; i < b; ++i) {
        float v = h[(size_t)i * 128 + t];
        sum += v;
        mx = fmaxf(mx, v);
    }
    sg[t]       = sum / fmaxf((float)(b - a), 1.f);
    sg[128 + t] = (b > a) ? mx : 0.f;
    __syncthreads();
    float acc = b1[t];
    for (int i = 0; i < 256; ++i) acc += sg[i] * w1[i * 128 + t];
    float ga = bnp[t], be = bnp[128 + t], m = bnp[256 + t], va = bnp[384 + t];
    acc = ga * (acc - m) * rsqrtf(va + 1e-5f) + be;
    sz1[t] = fmaxf(acc, 0.f);
    __syncthreads();
    if (t < 64) {
        float a2 = b2[t];
        for (int i = 0; i < 128; ++i) a2 += sz1[i] * w2[i * 64 + t];
        sz2[t] = fmaxf(a2, 0.f);
    }
    __syncthreads();
    if (t < 2) {
        float a3 = b3[t];
        for (int i = 0; i < 64; ++i) a3 += sz2[i] * w3[i * 2 + t];
        sz3[t] = a3;
    }
    __syncthreads();
    if (t < 2) {
        float mm = fmaxf(sz3[0], sz3[1]);
        float lse = mm + logf(expf(sz3[0] - mm) + expf(sz3[1] - mm));
        out[g * 2 + t] = sz3[t] - lse;
    }
}

// ---------------------------------------------------------------------------
// launch: 10 kernels total
// ---------------------------------------------------------------------------
extern "C" void kernel_launch(void* const* d_in, const int* in_sizes, int n_in,
                              void* d_out, int out_size, void* d_ws, size_t ws_size,
                              hipStream_t stream) {
    const float* x       = (const float*)d_in[0];
    const int*   ei      = (const int*)d_in[1];
    const int*   batch   = (const int*)d_in[2];
    const float* w_in    = (const float*)d_in[3];
    const float* b_in    = (const float*)d_in[4];
    const float* bn_in   = (const float*)d_in[5];
    const float* g1_wl   = (const float*)d_in[6];
    const float* g1_bl   = (const float*)d_in[7];
    const float* g1_wr   = (const float*)d_in[8];
    const float* g1_br   = (const float*)d_in[9];
    const float* g1_att  = (const float*)d_in[10];
    const float* g1_bias = (const float*)d_in[11];
    const float* bn1     = (const float*)d_in[12];
    const float* g2_wl   = (const float*)d_in[13];
    const float* g2_bl   = (const float*)d_in[14];
    const float* g2_wr   = (const float*)d_in[15];
    const float* g2_br   = (const float*)d_in[16];
    const float* g2_att  = (const float*)d_in[17];
    const float* g2_bias = (const float*)d_in[18];
    const float* bn2     = (const float*)d_in[19];
    const float* g3_wl   = (const float*)d_in[20];
    const float* g3_bl   = (const float*)d_in[21];
    const float* g3_wr   = (const float*)d_in[22];
    const float* g3_br   = (const float*)d_in[23];
    const float* g3_att  = (const float*)d_in[24];
    const float* g3_bias = (const float*)d_in[25];
    const float* bn3     = (const float*)d_in[26];
    const float* c_w1    = (const float*)d_in[27];
    const float* c_b1    = (const float*)d_in[28];
    const float* c_bn    = (const float*)d_in[29];
    const float* c_w2    = (const float*)d_in[30];
    const float* c_b2    = (const float*)d_in[31];
    const float* c_w3    = (const float*)d_in[32];
    const float* c_b3    = (const float*)d_in[33];
    float* out = (float*)d_out;

    // ---- workspace layout
    const size_t NHC = (size_t)N_NODES * 256;
    _Float16* a16  = (_Float16*)d_ws;
    _Float16* xl16 = a16 + NHC;
    _Float16* xr16 = xl16 + NHC;
    _Float16* wt = xr16 + NHC;
    _Float16* wt1l = wt;            _Float16* wt1r = wt + 16384;
    _Float16* wt2l = wt + 32768;    _Float16* wt2r = wt + 98304;
    _Float16* wt3l = wt + 163840;   _Float16* wt3r = wt + 196608;
    float* fbase = (float*)(wt + 262144);
    float* bufD = fbase;
    int* iw = (int*)(bufD + (size_t)N_NODES * 128);
    int* deg       = iw;            int* cnt    = iw + 30000;   // contiguous pair
    int* row_start = iw + 90128;
    int* esrc      = iw + 120129;
    int* gstart    = iw + 390429;

    const int BT = 256;
    const int NT128 = cdiv(N_NODES, 128);      // 235

    // K1: init + weight prep
    init_wprep<<<512, BT, 0, stream>>>(deg, g1_wl, g1_wr, g2_wl, g2_wr,
                                       g3_wl, g3_wr, wt1l, wt1r, wt2l, wt2r, wt3l, wt3r);
    // K2: degree histogram + input layer
    hist_input<<<1024, BT, 0, stream>>>(ei, deg, x, w_in, b_in, bn_in, a16);
    // K3: row_start scan + gstart binary search
    scan_all<<<NCH, 256, 0, stream>>>(deg, batch, row_start, gstart);

    // K4: GAT layer-1 GEMM + fused CSR scatter (extra y-slice)
    gemm_mfma<64, 256, 1><<<dim3(NT128, 5), 256, 0, stream>>>(
        a16, wt1l, g1_bl, wt1r, g1_br, xl16, xr16, ei, row_start, cnt, esrc, N_NODES);
    // K5: gather 1
    gat_gather<4, 64, _Float16><<<cdiv(N_NODES * 64, BT), BT, 0, stream>>>(
        xl16, xr16, row_start, esrc, g1_att, g1_bias, bn1, a16);

    // K6/K7: GAT layer 2
    gemm_mfma<256, 256, 0><<<dim3(NT128, 4), 256, 0, stream>>>(
        a16, wt2l, g2_bl, wt2r, g2_br, xl16, xr16, nullptr, nullptr, nullptr, nullptr, N_NODES);
    gat_gather<4, 64, _Float16><<<cdiv(N_NODES * 64, BT), BT, 0, stream>>>(
        xl16, xr16, row_start, esrc, g2_att, g2_bias, bn2, a16);

    // K8/K9: GAT layer 3 (gather emits f32 for pooling)
    gemm_mfma<256, 128, 0><<<dim3(NT128, 2), 256, 0, stream>>>(
        a16, wt3l, g3_bl, wt3r, g3_br, xl16, xr16, nullptr, nullptr, nullptr, nullptr, N_NODES);
    gat_gather<1, 128, float><<<cdiv(N_NODES * 64, BT), BT, 0, stream>>>(
        xl16, xr16, row_start, esrc, g3_att, g3_bias, bn3, bufD);

    // K10: fused pooling + classifier
    pool_cls<<<N_GRAPHS, 128, 0, stream>>>(bufD, gstart, c_w1, c_b1, c_bn,
                                           c_w2, c_b2, c_w3, c_b3, out);
}

// Round 11
// 370.591 us; speedup vs baseline: 3.6080x; 1.0405x over previous
//
#include <hip/hip_runtime.h>
#include <math.h>

#define N_NODES  30000
#define N_EDGES  240000
#define E_TOT    270000   // N_EDGES + N_NODES self loops
#define N_GRAPHS 300
#define NCH      118      // cdiv(N_NODES, 256)

typedef _Float16 half8 __attribute__((ext_vector_type(8)));
typedef _Float16 half4 __attribute__((ext_vector_type(4)));
typedef _Float16 half2v __attribute__((ext_vector_type(2)));
typedef float float4v __attribute__((ext_vector_type(4)));

static inline int cdiv(int a, int b) { return (a + b - 1) / b; }

// ---------------------------------------------------------------------------
// K2: degree histogram + ALL weight transposes + input layer (K=5 GEMM).
// (deg/cnt zeroed by a hipMemsetAsync node before this kernel.)
// ---------------------------------------------------------------------------
__device__ inline void wp_dev(const float* __restrict__ W, _Float16* __restrict__ Wt,
                              int K, int CO, int gtid, int T) {
    int tot = K * CO;
    for (int i = gtid; i < tot; i += T) {
        int k = i / CO, c = i - k * CO;
        Wt[(size_t)c * K + k] = (_Float16)W[i];
    }
}

__global__ void hist_wprep_input(const int* __restrict__ ei, int* __restrict__ deg,
                                 const float* __restrict__ x, const float* __restrict__ w_in,
                                 const float* __restrict__ b_in, const float* __restrict__ bn_in,
                                 _Float16* __restrict__ a16,
                                 const float* __restrict__ w1l, const float* __restrict__ w1r,
                                 const float* __restrict__ w2l, const float* __restrict__ w2r,
                                 const float* __restrict__ w3l, const float* __restrict__ w3r,
                                 _Float16* __restrict__ t1l, _Float16* __restrict__ t1r,
                                 _Float16* __restrict__ t2l, _Float16* __restrict__ t2r,
                                 _Float16* __restrict__ t3l, _Float16* __restrict__ t3r) {
    int gtid = blockIdx.x * blockDim.x + threadIdx.x;
    int T = gridDim.x * blockDim.x;
    for (int e = gtid; e < E_TOT; e += T) {
        int d = (e < N_EDGES) ? ei[N_EDGES + e] : e - N_EDGES;
        atomicAdd(&deg[d], 1);
    }
    wp_dev(w1l, t1l, 64, 256, gtid, T);
    wp_dev(w1r, t1r, 64, 256, gtid, T);
    wp_dev(w2l, t2l, 256, 256, gtid, T);
    wp_dev(w2r, t2r, 256, 256, gtid, T);
    wp_dev(w3l, t3l, 256, 128, gtid, T);
    wp_dev(w3r, t3r, 256, 128, gtid, T);

    int lane = threadIdx.x & 63;
    int wv = blockIdx.x * (blockDim.x >> 6) + (threadIdx.x >> 6);
    int NW = gridDim.x * (blockDim.x >> 6);
    float g = bn_in[lane], be = bn_in[64 + lane];
    float m = bn_in[128 + lane], va = bn_in[192 + lane];
    float rs = rsqrtf(va + 1e-5f);
    float wcol[5];
#pragma unroll
    for (int ci = 0; ci < 5; ++ci) wcol[ci] = w_in[ci * 64 + lane];
    float bb = b_in[lane];
    for (int n = wv; n < N_NODES; n += NW) {
        float xv = (lane < 5) ? x[n * 5 + lane] : 0.f;
        float acc = bb;
#pragma unroll
        for (int ci = 0; ci < 5; ++ci)
            acc = fmaf(__shfl(xv, ci, 64), wcol[ci], acc);
        acc = g * (acc - m) * rs + be;
        a16[(size_t)n * 64 + lane] = (_Float16)fmaxf(acc, 0.f);
    }
}

// ---------------------------------------------------------------------------
// K3: one-launch scan. Block b sums deg[0..b*256) (L2-resident) + local
// chunk scan -> row_start. Block 0 binary-searches gstart (batch sorted).
// ---------------------------------------------------------------------------
__global__ __launch_bounds__(256)
void scan_all(const int* __restrict__ deg, const int* __restrict__ batch,
              int* __restrict__ row_start, int* __restrict__ gstart) {
    __shared__ int red[256];
    __shared__ int s[256];
    const int b = blockIdx.x, t = threadIdx.x;
    int pre = 0;
    for (int i = t; i < b * 256; i += 256) pre += deg[i];
    red[t] = pre;
    __syncthreads();
    for (int off = 128; off; off >>= 1) {
        if (t < off) red[t] += red[t + off];
        __syncthreads();
    }
    int base = red[0];
    int gid = b * 256 + t;
    int v = (gid < N_NODES) ? deg[gid] : 0;
    s[t] = v;
    __syncthreads();
    for (int off = 1; off < 256; off <<= 1) {
        int u = (t >= off) ? s[t - off] : 0;
        __syncthreads();
        s[t] += u;
        __syncthreads();
    }
    if (gid < N_NODES) row_start[gid] = base + s[t] - v;
    if (b == 0 && t == 0) row_start[N_NODES] = E_TOT;
    if (b == 0) {
        for (int g = t; g <= N_GRAPHS; g += 256) {
            int lo = 0, hi = N_NODES;
            while (lo < hi) {
                int mid = (lo + hi) >> 1;
                if (batch[mid] < g) lo = mid + 1;
                else                hi = mid;
            }
            gstart[g] = lo;
        }
    }
}

// ---------------------------------------------------------------------------
// MFMA f16 pair GEMM (fp32 accumulate). SCAT=1 adds a blockIdx.y slice that
// performs the CSR scatter (independent work, hides under the GEMM).
// ---------------------------------------------------------------------------
template<int K, int COUT, int SCAT>
__global__ __launch_bounds__(256, 3)
void gemm_mfma(const _Float16* __restrict__ A,
               const _Float16* __restrict__ Wtl, const float* __restrict__ bl,
               const _Float16* __restrict__ Wtr, const float* __restrict__ br,
               _Float16* __restrict__ outl, _Float16* __restrict__ outr,
               const int* __restrict__ ei, const int* __restrict__ row_start,
               int* __restrict__ cnt, int* __restrict__ esrc, int N) {
    constexpr int BM = 128, BN = 128, BK = 64;
    constexpr int LDK = BK + 8;
    constexpr int CSL = COUT / BN > 0 ? COUT / BN : 1;
    if (SCAT && blockIdx.y == 2 * CSL) {       // scatter slice
        int gtid = blockIdx.x * blockDim.x + threadIdx.x;
        int T = gridDim.x * blockDim.x;
        for (int e = gtid; e < E_TOT; e += T) {
            int s, d;
            if (e < N_EDGES) { s = ei[e]; d = ei[N_EDGES + e]; }
            else             { s = e - N_EDGES; d = s; }
            int slot = row_start[d] + atomicAdd(&cnt[d], 1);
            esrc[slot] = s;
        }
        return;
    }
    __shared__ _Float16 As[BM][LDK];
    __shared__ _Float16 Bs[BN][LDK];
    const int tid  = threadIdx.x;
    const int wave = tid >> 6;
    const int lane = tid & 63;
    const int l15  = lane & 15;
    const int lq   = lane >> 4;
    const int n0   = blockIdx.x * BM;
    const int sel  = blockIdx.y / CSL;
    const int col0 = (blockIdx.y % CSL) * BN;
    const _Float16* Wt = sel ? Wtr : Wtl;
    const float* bias  = sel ? br : bl;
    _Float16* out      = sel ? outr : outl;

    float4v acc[2][8];
#pragma unroll
    for (int mi = 0; mi < 2; ++mi)
#pragma unroll
        for (int nt = 0; nt < 8; ++nt)
#pragma unroll
            for (int r = 0; r < 4; ++r) acc[mi][nt][r] = 0.f;

    for (int kt = 0; kt < K; kt += BK) {
#pragma unroll
        for (int p = 0; p < 4; ++p) {
            int idx = p * 256 + tid;
            int row = idx >> 3;
            int ch  = (idx & 7) * 8;
            int gn  = n0 + row;
            half8 v = {};
            if (gn < N) v = *(const half8*)(A + (size_t)gn * K + kt + ch);
            *(half8*)(&As[row][ch]) = v;
        }
#pragma unroll
        for (int p = 0; p < 4; ++p) {
            int idx = p * 256 + tid;
            int row = idx >> 3;
            int ch  = (idx & 7) * 8;
            half8 v = *(const half8*)(Wt + (size_t)(col0 + row) * K + kt + ch);
            *(half8*)(&Bs[row][ch]) = v;
        }
        __syncthreads();
#pragma unroll
        for (int kk = 0; kk < BK; kk += 32) {
            half8 af0 = *(const half8*)(&As[wave * 32 + l15][kk + lq * 8]);
            half8 af1 = *(const half8*)(&As[wave * 32 + 16 + l15][kk + lq * 8]);
#pragma unroll
            for (int nt = 0; nt < 8; ++nt) {
                half8 bf = *(const half8*)(&Bs[nt * 16 + l15][kk + lq * 8]);
                acc[0][nt] = __builtin_amdgcn_mfma_f32_16x16x32_f16(af0, bf, acc[0][nt], 0, 0, 0);
                acc[1][nt] = __builtin_amdgcn_mfma_f32_16x16x32_f16(af1, bf, acc[1][nt], 0, 0, 0);
            }
        }
        __syncthreads();
    }
#pragma unroll
    for (int mi = 0; mi < 2; ++mi)
#pragma unroll
        for (int nt = 0; nt < 8; ++nt) {
            int col = col0 + nt * 16 + l15;
            float bv = bias[col];
#pragma unroll
            for (int r = 0; r < 4; ++r) {
                int row = n0 + wave * 32 + mi * 16 + lq * 4 + r;
                if (row < N)
                    out[(size_t)row * COUT + col] = (_Float16)(acc[mi][nt][r] + bv);
            }
        }
}

// ---------------------------------------------------------------------------
// GATv2 gather (H=4): wave per node, NO max-subtraction (logits bounded
// |p|<~25 -> exp safe in f32; alpha mathematically identical). Each 4-edge
// batch is fully independent -> deep ILP/MLP, no serial rescale chain.
// ---------------------------------------------------------------------------
template<typename TOUT>
__global__ __launch_bounds__(256)
void gat_gather4(const _Float16* __restrict__ xl, const _Float16* __restrict__ xr,
                 const int* __restrict__ row_start, const int* __restrict__ esrc,
                 const float* __restrict__ att, const float* __restrict__ gbias,
                 const float* __restrict__ bnp, TOUT* __restrict__ out) {
    constexpr int HC = 256, PER = 4, GROUP = 16;
    int node = (blockIdx.x * blockDim.x + threadIdx.x) >> 6;
    int lane = threadIdx.x & 63;
    if (node >= N_NODES) return;
    const int base = lane * PER;

    float rr[PER], av[PER], acc[PER];
    {
        half4 rv = *(const half4*)(xr + (size_t)node * HC + base);
#pragma unroll
        for (int k = 0; k < PER; ++k) rr[k] = (float)rv[k];
        *(float4*)av = *(const float4*)(att + base);
    }
#pragma unroll
    for (int k = 0; k < PER; ++k) acc[k] = 0.f;

    float l = 0.f;
    const int j0 = row_start[node], j1 = row_start[node + 1];
    for (int jc = j0; jc < j1; jc += 64) {
        int nedge = min(64, j1 - jc);
        int ev = (jc + lane < j1) ? esrc[jc + lane] : 0;
        for (int jj = 0; jj < nedge; jj += 4) {
            int s[4];
            bool val[4];
#pragma unroll
            for (int u = 0; u < 4; ++u) {
                int idx = jj + u;
                val[u] = idx < nedge;
                s[u] = __shfl(ev, val[u] ? idx : jj, 64);
            }
            float xs[4][PER];
#pragma unroll
            for (int u = 0; u < 4; ++u) {
                half4 xv = *(const half4*)(xl + (size_t)s[u] * HC + base);
#pragma unroll
                for (int k = 0; k < PER; ++k) xs[u][k] = (float)xv[k];
            }
            float pz[4];
#pragma unroll
            for (int u = 0; u < 4; ++u) {
                float pp = 0.f;
#pragma unroll
                for (int k = 0; k < PER; ++k) {
                    float v = xs[u][k] + rr[k];
                    v = (v > 0.f) ? v : 0.2f * v;
                    pp = fmaf(v, av[k], pp);
                }
                pz[u] = pp;
            }
#pragma unroll
            for (int off = GROUP / 2; off; off >>= 1) {
#pragma unroll
                for (int u = 0; u < 4; ++u) pz[u] += __shfl_xor(pz[u], off, 64);
            }
            float w[4];
#pragma unroll
            for (int u = 0; u < 4; ++u) w[u] = val[u] ? __expf(pz[u]) : 0.f;
            l += (w[0] + w[1]) + (w[2] + w[3]);
#pragma unroll
            for (int k = 0; k < PER; ++k)
                acc[k] += fmaf(w[0], xs[0][k],
                          fmaf(w[1], xs[1][k],
                          fmaf(w[2], xs[2][k], w[3] * xs[3][k])));
        }
    }
    float inv = 1.f / (l + 1e-16f);
    float o[PER];
#pragma unroll
    for (int k = 0; k < PER; ++k) {
        float v = fmaf(acc[k], inv, gbias[base + k]);
        float g  = bnp[base + k], be = bnp[HC + base + k];
        float mm = bnp[2 * HC + base + k], va = bnp[3 * HC + base + k];
        v = g * (v - mm) * rsqrtf(va + 1e-5f) + be;
        o[k] = (v > 0.f) ? v : (__expf(v) - 1.f);
    }
    half4 ov;
#pragma unroll
    for (int k = 0; k < PER; ++k) ov[k] = (_Float16)o[k];
    *(half4*)((_Float16*)out + (size_t)node * HC + base) = ov;
}

// ---------------------------------------------------------------------------
// GATv2 gather (H=1, C=128): DUAL-EDGE wave. Lanes split into two 32-lane
// halves; each half owns 4 channels/lane (covers 128 ch) and processes its
// own edge -> 2 edges per step, 5-hop reduction (xor<=16 stays in-half).
// Halves combined once per node via shfl_xor(32). No max-subtraction.
// ---------------------------------------------------------------------------
__global__ __launch_bounds__(256)
void gat_gather1(const _Float16* __restrict__ xl, const _Float16* __restrict__ xr,
                 const int* __restrict__ row_start, const int* __restrict__ esrc,
                 const float* __restrict__ att, const float* __restrict__ gbias,
                 const float* __restrict__ bnp, float* __restrict__ out) {
    constexpr int HC = 128, PER = 4;
    int node = (blockIdx.x * blockDim.x + threadIdx.x) >> 6;
    int lane = threadIdx.x & 63;
    if (node >= N_NODES) return;
    const int half = lane >> 5;
    const int base = (lane & 31) * PER;

    float rr[PER], av[PER], acc[PER];
    {
        half4 rv = *(const half4*)(xr + (size_t)node * HC + base);
#pragma unroll
        for (int k = 0; k < PER; ++k) rr[k] = (float)rv[k];
        *(float4*)av = *(const float4*)(att + base);
    }
#pragma unroll
    for (int k = 0; k < PER; ++k) acc[k] = 0.f;

    float l = 0.f;
    const int j0 = row_start[node], j1 = row_start[node + 1];
    for (int jc = j0; jc < j1; jc += 64) {
        int nedge = min(64, j1 - jc);
        int ev = (jc + lane < j1) ? esrc[jc + lane] : 0;
        for (int jj = 0; jj < nedge; jj += 8) {          // 8 edges: 4 per half
            int s[4];
            bool val[4];
#pragma unroll
            for (int u = 0; u < 4; ++u) {
                int idx = jj + 2 * u + half;
                val[u] = idx < nedge;
                s[u] = __shfl(ev, val[u] ? idx : jj, 64);
            }
            float xs[4][PER];
#pragma unroll
            for (int u = 0; u < 4; ++u) {
                half4 xv = *(const half4*)(xl + (size_t)s[u] * HC + base);
#pragma unroll
                for (int k = 0; k < PER; ++k) xs[u][k] = (float)xv[k];
            }
            float pz[4];
#pragma unroll
            for (int u = 0; u < 4; ++u) {
                float pp = 0.f;
#pragma unroll
                for (int k = 0; k < PER; ++k) {
                    float v = xs[u][k] + rr[k];
                    v = (v > 0.f) ? v : 0.2f * v;
                    pp = fmaf(v, av[k], pp);
                }
                pz[u] = pp;
            }
#pragma unroll
            for (int off = 16; off; off >>= 1) {         // 5 hops, in-half
#pragma unroll
                for (int u = 0; u < 4; ++u) pz[u] += __shfl_xor(pz[u], off, 64);
            }
            float w[4];
#pragma unroll
            for (int u = 0; u < 4; ++u) w[u] = val[u] ? __expf(pz[u]) : 0.f;
            l += (w[0] + w[1]) + (w[2] + w[3]);
#pragma unroll
            for (int k = 0; k < PER; ++k)
                acc[k] += fmaf(w[0], xs[0][k],
                          fmaf(w[1], xs[1][k],
                          fmaf(w[2], xs[2][k], w[3] * xs[3][k])));
        }
    }
    // combine the two halves (disjoint edge sets, same channels)
    l += __shfl_xor(l, 32, 64);
#pragma unroll
    for (int k = 0; k < PER; ++k) acc[k] += __shfl_xor(acc[k], 32, 64);

    if (half == 0) {
        float inv = 1.f / (l + 1e-16f);
        float o[PER];
#pragma unroll
        for (int k = 0; k < PER; ++k) {
            float v = fmaf(acc[k], inv, gbias[base + k]);
            float g  = bnp[base + k], be = bnp[HC + base + k];
            float mm = bnp[2 * HC + base + k], va = bnp[3 * HC + base + k];
            v = g * (v - mm) * rsqrtf(va + 1e-5f) + be;
            o[k] = (v > 0.f) ? v : (__expf(v) - 1.f);
        }
        *(float4*)(out + (size_t)node * HC + base) = *(float4*)o;
    }
}

// ---------------------------------------------------------------------------
// K10: fused pooling + classifier, one block (128 threads) per graph
// ---------------------------------------------------------------------------
__global__ void pool_cls(const float* __restrict__ h, const int* __restrict__ gstart,
                         const float* __restrict__ w1, const float* __restrict__ b1,
                         const float* __restrict__ bnp,
                         const float* __restrict__ w2, const float* __restrict__ b2,
                         const float* __restrict__ w3, const float* __restrict__ b3,
                         float* __restrict__ out) {
    __shared__ float sg[256];
    __shared__ float sz1[128];
    __shared__ float sz2[64];
    __shared__ float sz3[2];
    int g = blockIdx.x, t = threadIdx.x;
    int a = gstart[g], b = gstart[g + 1];
    float sum = 0.f, mx = -INFINITY;
    for (int i = a; i < b; ++i) {
        float v = h[(size_t)i * 128 + t];
        sum += v;
        mx = fmaxf(mx, v);
    }
    sg[t]       = sum / fmaxf((float)(b - a), 1.f);
    sg[128 + t] = (b > a) ? mx : 0.f;
    __syncthreads();
    float acc = b1[t];
    for (int i = 0; i < 256; ++i) acc += sg[i] * w1[i * 128 + t];
    float ga = bnp[t], be = bnp[128 + t], m = bnp[256 + t], va = bnp[384 + t];
    acc = ga * (acc - m) * rsqrtf(va + 1e-5f) + be;
    sz1[t] = fmaxf(acc, 0.f);
    __syncthreads();
    if (t < 64) {
        float a2 = b2[t];
        for (int i = 0; i < 128; ++i) a2 += sz1[i] * w2[i * 64 + t];
        sz2[t] = fmaxf(a2, 0.f);
    }
    __syncthreads();
    if (t < 2) {
        float a3 = b3[t];
        for (int i = 0; i < 64; ++i) a3 += sz2[i] * w3[i * 2 + t];
        sz3[t] = a3;
    }
    __syncthreads();
    if (t < 2) {
        float mm = fmaxf(sz3[0], sz3[1]);
        float lse = mm + logf(expf(sz3[0] - mm) + expf(sz3[1] - mm));
        out[g * 2 + t] = sz3[t] - lse;
    }
}

// ---------------------------------------------------------------------------
// launch: 1 memset + 9 kernels
// ---------------------------------------------------------------------------
extern "C" void kernel_launch(void* const* d_in, const int* in_sizes, int n_in,
                              void* d_out, int out_size, void* d_ws, size_t ws_size,
                              hipStream_t stream) {
    const float* x       = (const float*)d_in[0];
    const int*   ei      = (const int*)d_in[1];
    const int*   batch   = (const int*)d_in[2];
    const float* w_in    = (const float*)d_in[3];
    const float* b_in    = (const float*)d_in[4];
    const float* bn_in   = (const float*)d_in[5];
    const float* g1_wl   = (const float*)d_in[6];
    const float* g1_bl   = (const float*)d_in[7];
    const float* g1_wr   = (const float*)d_in[8];
    const float* g1_br   = (const float*)d_in[9];
    const float* g1_att  = (const float*)d_in[10];
    const float* g1_bias = (const float*)d_in[11];
    const float* bn1     = (const float*)d_in[12];
    const float* g2_wl   = (const float*)d_in[13];
    const float* g2_bl   = (const float*)d_in[14];
    const float* g2_wr   = (const float*)d_in[15];
    const float* g2_br   = (const float*)d_in[16];
    const float* g2_att  = (const float*)d_in[17];
    const float* g2_bias = (const float*)d_in[18];
    const float* bn2     = (const float*)d_in[19];
    const float* g3_wl   = (const float*)d_in[20];
    const float* g3_bl   = (const float*)d_in[21];
    const float* g3_wr   = (const float*)d_in[22];
    const float* g3_br   = (const float*)d_in[23];
    const float* g3_att  = (const float*)d_in[24];
    const float* g3_bias = (const float*)d_in[25];
    const float* bn3     = (const float*)d_in[26];
    const float* c_w1    = (const float*)d_in[27];
    const float* c_b1    = (const float*)d_in[28];
    const float* c_bn    = (const float*)d_in[29];
    const float* c_w2    = (const float*)d_in[30];
    const float* c_b2    = (const float*)d_in[31];
    const float* c_w3    = (const float*)d_in[32];
    const float* c_b3    = (const float*)d_in[33];
    float* out = (float*)d_out;

    // ---- workspace layout
    const size_t NHC = (size_t)N_NODES * 256;
    _Float16* a16  = (_Float16*)d_ws;
    _Float16* xl16 = a16 + NHC;
    _Float16* xr16 = xl16 + NHC;
    _Float16* wt = xr16 + NHC;
    _Float16* wt1l = wt;            _Float16* wt1r = wt + 16384;
    _Float16* wt2l = wt + 32768;    _Float16* wt2r = wt + 98304;
    _Float16* wt3l = wt + 163840;   _Float16* wt3r = wt + 196608;
    float* fbase = (float*)(wt + 262144);
    float* bufD = fbase;
    int* iw = (int*)(bufD + (size_t)N_NODES * 128);
    int* deg       = iw;            int* cnt    = iw + 30000;   // contiguous pair
    int* row_start = iw + 90128;
    int* esrc      = iw + 120129;
    int* gstart    = iw + 390429;

    const int BT = 256;
    const int NT128 = cdiv(N_NODES, 128);      // 235

    // N0: zero deg+cnt (memset node: cheaper than a kernel launch)
    hipMemsetAsync(deg, 0, 60000 * sizeof(int), stream);

    // K1: histogram + weight prep + input layer
    hist_wprep_input<<<1024, BT, 0, stream>>>(ei, deg, x, w_in, b_in, bn_in, a16,
                                              g1_wl, g1_wr, g2_wl, g2_wr, g3_wl, g3_wr,
                                              wt1l, wt1r, wt2l, wt2r, wt3l, wt3r);
    // K2: row_start scan + gstart binary search
    scan_all<<<NCH, 256, 0, stream>>>(deg, batch, row_start, gstart);

    // K3: GAT layer-1 GEMM + fused CSR scatter (extra y-slice)
    gemm_mfma<64, 256, 1><<<dim3(NT128, 5), 256, 0, stream>>>(
        a16, wt1l, g1_bl, wt1r, g1_br, xl16, xr16, ei, row_start, cnt, esrc, N_NODES);
    // K4: gather 1
    gat_gather4<_Float16><<<cdiv(N_NODES * 64, BT), BT, 0, stream>>>(
        xl16, xr16, row_start, esrc, g1_att, g1_bias, bn1, a16);

    // K5/K6: GAT layer 2
    gemm_mfma<256, 256, 0><<<dim3(NT128, 4), 256, 0, stream>>>(
        a16, wt2l, g2_bl, wt2r, g2_br, xl16, xr16, nullptr, nullptr, nullptr, nullptr, N_NODES);
    gat_gather4<_Float16><<<cdiv(N_NODES * 64, BT), BT, 0, stream>>>(
        xl16, xr16, row_start, esrc, g2_att, g2_bias, bn2, a16);

    // K7/K8: GAT layer 3 (dual-edge gather emits f32 for pooling)
    gemm_mfma<256, 128, 0><<<dim3(NT128, 2), 256, 0, stream>>>(
        a16, wt3l, g3_bl, wt3r, g3_br, xl16, xr16, nullptr, nullptr, nullptr, nullptr, N_NODES);
    gat_gather1<<<cdiv(N_NODES * 64, BT), BT, 0, stream>>>(
        xl16, xr16, row_start, esrc, g3_att, g3_bias, bn3, bufD);

    // K9: fused pooling + classifier
    pool_cls<<<N_GRAPHS, 128, 0, stream>>>(bufD, gstart, c_w1, c_b1, c_bn,
                                           c_w2, c_b2, c_w3, c_b3, out);
}